// Round 4
// baseline (2016.441 us; speedup 1.0000x reference)
//
#include <hip/hip_runtime.h>
#include <hip/hip_fp16.h>
#include <math.h>

typedef _Float16 f16x8 __attribute__((ext_vector_type(8)));
typedef _Float16 f16x4 __attribute__((ext_vector_type(4)));
typedef float f32x4 __attribute__((ext_vector_type(4)));

// ================= bucketed CSR build =================
#define BSH 9
#define BSZ 512

// passA: bucket histogram only (LDS atomics)
__global__ __launch_bounds__(256) void passA(const int* __restrict__ ei,
                                             int* __restrict__ bcount, int E, int NB) {
  __shared__ int hist[256];
  int t = threadIdx.x;
  hist[t] = 0;
  __syncthreads();
  for (int e = blockIdx.x * 256 + t; e < E; e += gridDim.x * 256)
    atomicAdd(&hist[ei[E + e] >> BSH], 1);
  __syncthreads();
  if (t < NB && hist[t]) atomicAdd(&bcount[t], hist[t]);
}

__global__ __launch_bounds__(256) void scanB(const int* __restrict__ bcount,
                                             int* __restrict__ bstart,
                                             int* __restrict__ bfill, int NB, int E) {
  __shared__ int s[256];
  int t = threadIdx.x;
  int v = (t < NB) ? bcount[t] : 0;
  s[t] = v;
  __syncthreads();
  for (int off = 1; off < 256; off <<= 1) {
    int add = (t >= off) ? s[t - off] : 0;
    __syncthreads();
    s[t] += add;
    __syncthreads();
  }
  if (t < NB) {
    int ex = s[t] - v;
    bstart[t] = ex;
    bfill[t] = ex;
  }
  if (t == 0) bstart[NB] = E;
}

// ===== MFMA GEMM body =====
// Output G is SLICE-MAJOR: [NC/16 slices][nrows][16] f16.
// f16 input (IN_F16) is also slice-major [8][nrows][16].
template <int NC, int NWC, bool IN_F16, bool SCALE>
__device__ __forceinline__ void gemm_mfma_body(
    const void* __restrict__ Xv, const float* __restrict__ W,
    const int* __restrict__ deg, _Float16* __restrict__ G, int nrows, int bid,
    _Float16* Bs) {
  int t = threadIdx.x;
  {
    int n = t % NC;
    int kh = (t / NC) * (NC / 2);
    constexpr int NBLK = (NC / 2) / 8;
#pragma unroll
    for (int b = 0; b < NBLK; ++b) {
      f16x8 tmp;
#pragma unroll
      for (int j = 0; j < 8; ++j)
        tmp[j] = (_Float16)W[(size_t)(kh + b * 8 + j) * NC + n];
      *(f16x8*)(&Bs[n * 136 + kh + b * 8]) = tmp;
    }
  }
  __syncthreads();

  int w = t >> 6, lane = t & 63;
  int m = lane & 15, q = lane >> 4;
  int wr = (w / NWC) * 64, wc = (w % NWC) * 64;
  int row0 = bid * ((4 / NWC) * 64);

  f32x4 acc[4][4];
#pragma unroll
  for (int rt = 0; rt < 4; ++rt)
#pragma unroll
    for (int ct = 0; ct < 4; ++ct)
#pragma unroll
      for (int qq = 0; qq < 4; ++qq) acc[rt][ct][qq] = 0.f;

#pragma unroll
  for (int kc = 0; kc < 4; ++kc) {
    int kbase = kc * 32 + q * 8;
    f16x8 af[4];
#pragma unroll
    for (int rt = 0; rt < 4; ++rt) {
      int row = row0 + wr + rt * 16 + m;
      if constexpr (IN_F16) {
        // slice-major input: channels kbase..kbase+8 live in slice kbase>>4
        f16x8 a = {0, 0, 0, 0, 0, 0, 0, 0};
        if (row < nrows) {
          const _Float16* Xh = (const _Float16*)Xv;
          a = *(const f16x8*)(Xh + ((size_t)(kbase >> 4) * nrows + row) * 16 +
                              (kbase & 15));
        }
        af[rt] = a;
      } else {
        float4 x0 = {0, 0, 0, 0}, x1 = {0, 0, 0, 0};
        if (row < nrows) {
          const float* Xf = (const float*)Xv;
          x0 = *(const float4*)(Xf + (size_t)row * 128 + kbase);
          x1 = *(const float4*)(Xf + (size_t)row * 128 + kbase + 4);
        }
        f16x8 a;
        a[0] = (_Float16)x0.x; a[1] = (_Float16)x0.y;
        a[2] = (_Float16)x0.z; a[3] = (_Float16)x0.w;
        a[4] = (_Float16)x1.x; a[5] = (_Float16)x1.y;
        a[6] = (_Float16)x1.z; a[7] = (_Float16)x1.w;
        af[rt] = a;
      }
    }
    f16x8 bf[4];
#pragma unroll
    for (int ct = 0; ct < 4; ++ct) {
      int n = wc + ct * 16 + m;
      bf[ct] = *(f16x8*)(&Bs[n * 136 + kbase]);
    }
#pragma unroll
    for (int rt = 0; rt < 4; ++rt)
#pragma unroll
      for (int ct = 0; ct < 4; ++ct)
        acc[rt][ct] = __builtin_amdgcn_mfma_f32_16x16x32_f16(af[rt], bf[ct],
                                                             acc[rt][ct], 0, 0, 0);
  }
#pragma unroll
  for (int rt = 0; rt < 4; ++rt) {
#pragma unroll
    for (int r = 0; r < 4; ++r) {
      int row = row0 + wr + rt * 16 + q * 4 + r;
      if (row < nrows) {
        float d = SCALE ? rsqrtf((float)deg[row] + 1.f) : 1.f;
#pragma unroll
        for (int ct = 0; ct < 4; ++ct) {
          // col = wc + ct*16 + m  ->  slice = col>>4, offset = m
          int slice = (wc >> 4) + ct;
          G[((size_t)slice * nrows + row) * 16 + m] =
              (_Float16)(acc[rt][ct][r] * d);
        }
      }
    }
  }
}

// ===== fused: gemm1 (MFMA, unscaled, fp32-in, sliced-out) + passB =====
__global__ __launch_bounds__(256) void fused_gemm_passB(
    const float* __restrict__ X, const float* __restrict__ W1,
    _Float16* __restrict__ G, int nrows, int GB,
    const int* __restrict__ ei, int* __restrict__ bfill,
    unsigned int* __restrict__ pairs, int E, int PB) {
  __shared__ char smem[128 * 136 * 2];
  int g = blockIdx.x;
  int M2 = 2 * (GB < PB ? GB : PB);
  bool is_gemm;
  int bid;
  if (g < M2) { is_gemm = (g & 1) == 0; bid = g >> 1; }
  else        { is_gemm = (GB > PB);    bid = g - M2 + (GB < PB ? GB : PB); }
  if (is_gemm) {
    gemm_mfma_body<128, 2, false, false>(X, W1, nullptr, G, nrows, bid,
                                         (_Float16*)smem);
  } else {
    int* hist = (int*)smem;
    int* gbase = (int*)(smem + 1024);
    int t = threadIdx.x;
    hist[t] = 0;
    __syncthreads();
    int d[8], s[8], lp[8], bb[8];
    int base = bid * 2048;
#pragma unroll
    for (int u = 0; u < 8; ++u) {
      int e = base + u * 256 + t;
      if (e < E) {
        d[u] = ei[E + e];
        s[u] = ei[e];
        bb[u] = d[u] >> BSH;
        lp[u] = atomicAdd(&hist[bb[u]], 1);
      } else {
        bb[u] = -1;
      }
    }
    __syncthreads();
    if (hist[t]) gbase[t] = atomicAdd(&bfill[t], hist[t]);
    __syncthreads();
#pragma unroll
    for (int u = 0; u < 8; ++u)
      if (bb[u] >= 0)
        pairs[gbase[bb[u]] + lp[u]] =
            ((unsigned int)(d[u] & (BSZ - 1)) << 17) | (unsigned int)s[u];
  }
}

__global__ __launch_bounds__(256) void gemm2_mfma(const _Float16* __restrict__ X,
                                                  const float* __restrict__ W,
                                                  const int* __restrict__ deg,
                                                  _Float16* __restrict__ G, int nrows) {
  __shared__ _Float16 Bs[64 * 136];
  gemm_mfma_body<64, 1, true, true>(X, W, deg, G, nrows, blockIdx.x, Bs);
}

// passC: per-bucket degree count + deg write + in-place sliced-G prescale
__global__ __launch_bounds__(512) void passC(const unsigned int* __restrict__ pairs,
                                             const int* __restrict__ bstart,
                                             int* __restrict__ deg,
                                             _Float16* __restrict__ G, int N) {
  __shared__ int hcnt[BSZ];
  __shared__ float sdinv[BSZ];
  int b = blockIdx.x;
  int t = threadIdx.x;
  int lo = bstart[b], hi = bstart[b + 1];
  int nbase = b << BSH;
  hcnt[t] = 0;
  __syncthreads();
  for (int k = lo + t; k < hi; k += 512)
    atomicAdd(&hcnt[(pairs[k] >> 17) & (BSZ - 1)], 1);
  __syncthreads();
  int v = hcnt[t];
  sdinv[t] = rsqrtf((float)v + 1.f);
  int node = nbase + t;
  if (node < N) deg[node] = v;
  __syncthreads();
  int rows = N - nbase;
  if (rows > BSZ) rows = BSZ;
  // prescale: G[s][nbase..nbase+rows][*] *= sdinv  (8 slices, coalesced)
  for (int s = 0; s < 8; ++s) {
    _Float16* base = G + ((size_t)s * N + nbase) * 16;
    for (int idx = t; idx < rows * 2; idx += 512) {
      int r = idx >> 1, off = (idx & 1) * 8;
      float dv = sdinv[r];
      _Float16* p = base + (size_t)r * 16 + off;
      f16x8 vv = *(const f16x8*)p;
#pragma unroll
      for (int j = 0; j < 8; ++j) vv[j] = (_Float16)((float)vv[j] * dv);
      *(f16x8*)p = vv;
    }
  }
}

// ===== agg128s: XCD-local sliced gather, LDS f32 accumulation =====
// grid = NB*8; slice = blockIdx&7 (pins slice to one XCD via round-robin
// dispatch); bucket = blockIdx>>3. Each block: 512 dst nodes x 16 channels.
__global__ __launch_bounds__(256) void agg128s(
    const _Float16* __restrict__ Gs,           // [8][N][16] prescaled
    const unsigned int* __restrict__ pairs,
    const int* __restrict__ bstart,
    const int* __restrict__ deg,
    const float* __restrict__ bias,            // 128
    _Float16* __restrict__ x2s,                // [8][N][16] out
    int N) {
  __shared__ float acc[BSZ * 16];              // 32 KB
  int slice = blockIdx.x & 7;
  int b = blockIdx.x >> 3;
  int t = threadIdx.x;
  const _Float16* Gsl = Gs + (size_t)slice * N * 16;
  for (int i = t; i < BSZ * 16; i += 256) acc[i] = 0.f;
  __syncthreads();
  int lo = bstart[b], hi = bstart[b + 1];
  int h8 = (t & 1) * 8;
  int k = lo + (t >> 1);
  for (; k + 128 < hi; k += 256) {
    unsigned int p0 = pairs[k];
    unsigned int p1 = pairs[k + 128];
    int s0 = (int)(p0 & 0x1FFFFu);
    int s1 = (int)(p1 & 0x1FFFFu);
    f16x8 v0 = *(const f16x8*)(Gsl + (size_t)s0 * 16 + h8);
    f16x8 v1 = *(const f16x8*)(Gsl + (size_t)s1 * 16 + h8);
    float* a0 = acc + ((p0 >> 17) & (BSZ - 1)) * 16 + h8;
    float* a1 = acc + ((p1 >> 17) & (BSZ - 1)) * 16 + h8;
#pragma unroll
    for (int j = 0; j < 8; ++j) atomicAdd(&a0[j], (float)v0[j]);
#pragma unroll
    for (int j = 0; j < 8; ++j) atomicAdd(&a1[j], (float)v1[j]);
  }
  for (; k < hi; k += 128) {
    unsigned int p0 = pairs[k];
    int s0 = (int)(p0 & 0x1FFFFu);
    f16x8 v0 = *(const f16x8*)(Gsl + (size_t)s0 * 16 + h8);
    float* a0 = acc + ((p0 >> 17) & (BSZ - 1)) * 16 + h8;
#pragma unroll
    for (int j = 0; j < 8; ++j) atomicAdd(&a0[j], (float)v0[j]);
  }
  __syncthreads();
  // epilogue: x2s[slice][node][*] = relu(di*(self + acc) + bias)
  int nbase = b << BSH;
  for (int idx = t; idx < BSZ * 2; idx += 256) {
    int nl = idx >> 1, off = (idx & 1) * 8;
    int node = nbase + nl;
    if (node < N) {
      float di = rsqrtf((float)deg[node] + 1.f);
      f16x8 sv = *(const f16x8*)(Gsl + (size_t)node * 16 + off);
      const float* ap = acc + nl * 16 + off;
      const float* bp = bias + slice * 16 + off;
      f16x8 r;
#pragma unroll
      for (int j = 0; j < 8; ++j) {
        float val = fmaf(di, (float)sv[j] + ap[j], bp[j]);
        r[j] = (_Float16)fmaxf(val, 0.f);
      }
      *(f16x8*)(x2s + ((size_t)slice * N + node) * 16 + off) = r;
    }
  }
}

// ===== agg64s: same scheme, 4 slices (2 XCDs per slice), row-major f32 out =====
__global__ __launch_bounds__(256) void agg64s(
    const _Float16* __restrict__ Gs,           // [4][N][16] dinv-prescaled
    const unsigned int* __restrict__ pairs,
    const int* __restrict__ bstart,
    const int* __restrict__ deg,
    const float* __restrict__ bias,            // 64
    float* __restrict__ out,                   // [N][64]
    int N) {
  __shared__ float acc[BSZ * 16];
  int slice = blockIdx.x & 3;
  int b = blockIdx.x >> 2;
  int t = threadIdx.x;
  const _Float16* Gsl = Gs + (size_t)slice * N * 16;
  for (int i = t; i < BSZ * 16; i += 256) acc[i] = 0.f;
  __syncthreads();
  int lo = bstart[b], hi = bstart[b + 1];
  int h8 = (t & 1) * 8;
  int k = lo + (t >> 1);
  for (; k + 128 < hi; k += 256) {
    unsigned int p0 = pairs[k];
    unsigned int p1 = pairs[k + 128];
    int s0 = (int)(p0 & 0x1FFFFu);
    int s1 = (int)(p1 & 0x1FFFFu);
    f16x8 v0 = *(const f16x8*)(Gsl + (size_t)s0 * 16 + h8);
    f16x8 v1 = *(const f16x8*)(Gsl + (size_t)s1 * 16 + h8);
    float* a0 = acc + ((p0 >> 17) & (BSZ - 1)) * 16 + h8;
    float* a1 = acc + ((p1 >> 17) & (BSZ - 1)) * 16 + h8;
#pragma unroll
    for (int j = 0; j < 8; ++j) atomicAdd(&a0[j], (float)v0[j]);
#pragma unroll
    for (int j = 0; j < 8; ++j) atomicAdd(&a1[j], (float)v1[j]);
  }
  for (; k < hi; k += 128) {
    unsigned int p0 = pairs[k];
    int s0 = (int)(p0 & 0x1FFFFu);
    f16x8 v0 = *(const f16x8*)(Gsl + (size_t)s0 * 16 + h8);
    float* a0 = acc + ((p0 >> 17) & (BSZ - 1)) * 16 + h8;
#pragma unroll
    for (int j = 0; j < 8; ++j) atomicAdd(&a0[j], (float)v0[j]);
  }
  __syncthreads();
  // epilogue: out[node][slice*16+0..15] = relu(di*(self+acc)+bias), 16B stores
  int nbase = b << BSH;
  for (int idx = t; idx < BSZ * 4; idx += 256) {
    int nl = idx >> 2, qq = idx & 3;
    int node = nbase + nl;
    if (node < N) {
      float di = rsqrtf((float)deg[node] + 1.f);
      f16x4 sv = *(const f16x4*)(Gsl + (size_t)node * 16 + qq * 4);
      const float* ap = acc + nl * 16 + qq * 4;
      const float* bp = bias + slice * 16 + qq * 4;
      float4 r;
      r.x = fmaxf(fmaf(di, (float)sv[0] + ap[0], bp[0]), 0.f);
      r.y = fmaxf(fmaf(di, (float)sv[1] + ap[1], bp[1]), 0.f);
      r.z = fmaxf(fmaf(di, (float)sv[2] + ap[2], bp[2]), 0.f);
      r.w = fmaxf(fmaf(di, (float)sv[3] + ap[3], bp[3]), 0.f);
      *(float4*)(out + (size_t)node * 64 + slice * 16 + qq * 4) = r;
    }
  }
}

// ================= launch =================
extern "C" void kernel_launch(void* const* d_in, const int* in_sizes, int n_in,
                              void* d_out, int out_size, void* d_ws, size_t ws_size,
                              hipStream_t stream) {
  const float* x  = (const float*)d_in[0];
  const int*   ei = (const int*)d_in[1];
  const float* W1 = (const float*)d_in[2];
  const float* b1 = (const float*)d_in[3];
  const float* W2 = (const float*)d_in[4];
  const float* b2 = (const float*)d_in[5];
  float* out = (float*)d_out;

  const int N = in_sizes[0] / 128;
  const int E = in_sizes[1] / 2;
  const int NB = (N + BSZ - 1) >> BSH;

  char* base = (char*)d_ws;
  size_t off = 0;
  auto alloc = [&](size_t bytes) -> void* {
    void* p = base + off;
    off += (bytes + 255) & ~(size_t)255;
    return p;
  };
  int*          bcount   = (int*)alloc(256 * 4);
  int*          bstart   = (int*)alloc(260 * 4);
  int*          bfill    = (int*)alloc(256 * 4);
  int*          deg      = (int*)alloc((size_t)N * 4);
  unsigned int* pairs    = (unsigned int*)alloc((size_t)E * 4);
  __half*       g1       = (__half*)alloc((size_t)N * 128 * 2);  // sliced; reused for G2s
  __half*       x2       = (__half*)alloc((size_t)N * 128 * 2);  // sliced

  hipMemsetAsync(bcount, 0, 256 * 4, stream);
  passA<<<512, 256, 0, stream>>>(ei, bcount, E, NB);
  scanB<<<1, 256, 0, stream>>>(bcount, bstart, bfill, NB, E);

  int GB = (N + 127) / 128;
  int PB = (E + 2047) / 2048;
  fused_gemm_passB<<<GB + PB, 256, 0, stream>>>(x, W1, (_Float16*)g1, N, GB,
                                                ei, bfill, pairs, E, PB);
  passC<<<NB, 512, 0, stream>>>(pairs, bstart, deg, (_Float16*)g1, N);

  agg128s<<<NB * 8, 256, 0, stream>>>((const _Float16*)g1, pairs, bstart, deg,
                                      b1, (_Float16*)x2, N);
  int G2B = (N + 255) / 256;
  gemm2_mfma<<<G2B, 256, 0, stream>>>((const _Float16*)x2, W2, deg,
                                      (_Float16*)g1, N);
  agg64s<<<NB * 4, 256, 0, stream>>>((const _Float16*)g1, pairs, bstart, deg,
                                     b2, out, N);
}

// Round 5
// 413.975 us; speedup vs baseline: 4.8709x; 4.8709x over previous
//
#include <hip/hip_runtime.h>
#include <hip/hip_fp16.h>
#include <math.h>

typedef _Float16 f16x8 __attribute__((ext_vector_type(8)));
typedef _Float16 f16x4 __attribute__((ext_vector_type(4)));
typedef float f32x4 __attribute__((ext_vector_type(4)));

// ================= bucketed CSR build =================
#define BSH 9
#define BSZ 512
#define CAP 12288

// passA: bucket histogram only (LDS atomics)
__global__ __launch_bounds__(256) void passA(const int* __restrict__ ei,
                                             int* __restrict__ bcount, int E, int NB) {
  __shared__ int hist[256];
  int t = threadIdx.x;
  hist[t] = 0;
  __syncthreads();
  for (int e = blockIdx.x * 256 + t; e < E; e += gridDim.x * 256)
    atomicAdd(&hist[ei[E + e] >> BSH], 1);
  __syncthreads();
  if (t < NB && hist[t]) atomicAdd(&bcount[t], hist[t]);
}

__global__ __launch_bounds__(256) void scanB(const int* __restrict__ bcount,
                                             int* __restrict__ bstart,
                                             int* __restrict__ bfill, int NB, int E) {
  __shared__ int s[256];
  int t = threadIdx.x;
  int v = (t < NB) ? bcount[t] : 0;
  s[t] = v;
  __syncthreads();
  for (int off = 1; off < 256; off <<= 1) {
    int add = (t >= off) ? s[t - off] : 0;
    __syncthreads();
    s[t] += add;
    __syncthreads();
  }
  if (t < NB) {
    int ex = s[t] - v;
    bstart[t] = ex;
    bfill[t] = ex;
  }
  if (t == 0) bstart[NB] = E;
}

// ===== MFMA GEMM body =====
// Output G is SLICE-MAJOR: [NC/16 slices][nrows][16] f16.
// f16 input (IN_F16) is also slice-major [8][nrows][16].
template <int NC, int NWC, bool IN_F16, bool SCALE>
__device__ __forceinline__ void gemm_mfma_body(
    const void* __restrict__ Xv, const float* __restrict__ W,
    const int* __restrict__ deg, _Float16* __restrict__ G, int nrows, int bid,
    _Float16* Bs) {
  int t = threadIdx.x;
  {
    int n = t % NC;
    int kh = (t / NC) * (NC / 2);
    constexpr int NBLK = (NC / 2) / 8;
#pragma unroll
    for (int b = 0; b < NBLK; ++b) {
      f16x8 tmp;
#pragma unroll
      for (int j = 0; j < 8; ++j)
        tmp[j] = (_Float16)W[(size_t)(kh + b * 8 + j) * NC + n];
      *(f16x8*)(&Bs[n * 136 + kh + b * 8]) = tmp;
    }
  }
  __syncthreads();

  int w = t >> 6, lane = t & 63;
  int m = lane & 15, q = lane >> 4;
  int wr = (w / NWC) * 64, wc = (w % NWC) * 64;
  int row0 = bid * ((4 / NWC) * 64);

  f32x4 acc[4][4];
#pragma unroll
  for (int rt = 0; rt < 4; ++rt)
#pragma unroll
    for (int ct = 0; ct < 4; ++ct)
#pragma unroll
      for (int qq = 0; qq < 4; ++qq) acc[rt][ct][qq] = 0.f;

#pragma unroll
  for (int kc = 0; kc < 4; ++kc) {
    int kbase = kc * 32 + q * 8;
    f16x8 af[4];
#pragma unroll
    for (int rt = 0; rt < 4; ++rt) {
      int row = row0 + wr + rt * 16 + m;
      if constexpr (IN_F16) {
        // slice-major input: channels kbase..kbase+8 live in slice kbase>>4
        f16x8 a = {0, 0, 0, 0, 0, 0, 0, 0};
        if (row < nrows) {
          const _Float16* Xh = (const _Float16*)Xv;
          a = *(const f16x8*)(Xh + ((size_t)(kbase >> 4) * nrows + row) * 16 +
                              (kbase & 15));
        }
        af[rt] = a;
      } else {
        float4 x0 = {0, 0, 0, 0}, x1 = {0, 0, 0, 0};
        if (row < nrows) {
          const float* Xf = (const float*)Xv;
          x0 = *(const float4*)(Xf + (size_t)row * 128 + kbase);
          x1 = *(const float4*)(Xf + (size_t)row * 128 + kbase + 4);
        }
        f16x8 a;
        a[0] = (_Float16)x0.x; a[1] = (_Float16)x0.y;
        a[2] = (_Float16)x0.z; a[3] = (_Float16)x0.w;
        a[4] = (_Float16)x1.x; a[5] = (_Float16)x1.y;
        a[6] = (_Float16)x1.z; a[7] = (_Float16)x1.w;
        af[rt] = a;
      }
    }
    f16x8 bf[4];
#pragma unroll
    for (int ct = 0; ct < 4; ++ct) {
      int n = wc + ct * 16 + m;
      bf[ct] = *(f16x8*)(&Bs[n * 136 + kbase]);
    }
#pragma unroll
    for (int rt = 0; rt < 4; ++rt)
#pragma unroll
      for (int ct = 0; ct < 4; ++ct)
        acc[rt][ct] = __builtin_amdgcn_mfma_f32_16x16x32_f16(af[rt], bf[ct],
                                                             acc[rt][ct], 0, 0, 0);
  }
#pragma unroll
  for (int rt = 0; rt < 4; ++rt) {
#pragma unroll
    for (int r = 0; r < 4; ++r) {
      int row = row0 + wr + rt * 16 + q * 4 + r;
      if (row < nrows) {
        float d = SCALE ? rsqrtf((float)deg[row] + 1.f) : 1.f;
#pragma unroll
        for (int ct = 0; ct < 4; ++ct) {
          // col = wc + ct*16 + m  ->  slice = col>>4, offset = m
          int slice = (wc >> 4) + ct;
          G[((size_t)slice * nrows + row) * 16 + m] =
              (_Float16)(acc[rt][ct][r] * d);
        }
      }
    }
  }
}

// ===== fused: gemm1 (MFMA, unscaled, fp32-in, sliced-out) + passB =====
__global__ __launch_bounds__(256) void fused_gemm_passB(
    const float* __restrict__ X, const float* __restrict__ W1,
    _Float16* __restrict__ G, int nrows, int GB,
    const int* __restrict__ ei, int* __restrict__ bfill,
    unsigned int* __restrict__ pairs, int E, int PB) {
  __shared__ char smem[128 * 136 * 2];
  int g = blockIdx.x;
  int M2 = 2 * (GB < PB ? GB : PB);
  bool is_gemm;
  int bid;
  if (g < M2) { is_gemm = (g & 1) == 0; bid = g >> 1; }
  else        { is_gemm = (GB > PB);    bid = g - M2 + (GB < PB ? GB : PB); }
  if (is_gemm) {
    gemm_mfma_body<128, 2, false, false>(X, W1, nullptr, G, nrows, bid,
                                         (_Float16*)smem);
  } else {
    int* hist = (int*)smem;
    int* gbase = (int*)(smem + 1024);
    int t = threadIdx.x;
    hist[t] = 0;
    __syncthreads();
    int d[8], s[8], lp[8], bb[8];
    int base = bid * 2048;
#pragma unroll
    for (int u = 0; u < 8; ++u) {
      int e = base + u * 256 + t;
      if (e < E) {
        d[u] = ei[E + e];
        s[u] = ei[e];
        bb[u] = d[u] >> BSH;
        lp[u] = atomicAdd(&hist[bb[u]], 1);
      } else {
        bb[u] = -1;
      }
    }
    __syncthreads();
    if (hist[t]) gbase[t] = atomicAdd(&bfill[t], hist[t]);
    __syncthreads();
#pragma unroll
    for (int u = 0; u < 8; ++u)
      if (bb[u] >= 0)
        pairs[gbase[bb[u]] + lp[u]] =
            ((unsigned int)(d[u] & (BSZ - 1)) << 17) | (unsigned int)s[u];
  }
}

__global__ __launch_bounds__(256) void gemm2_mfma(const _Float16* __restrict__ X,
                                                  const float* __restrict__ W,
                                                  const int* __restrict__ deg,
                                                  _Float16* __restrict__ G, int nrows) {
  __shared__ _Float16 Bs[64 * 136];
  gemm_mfma_body<64, 1, true, true>(X, W, deg, G, nrows, blockIdx.x, Bs);
}

// passC: per-bucket LDS count/scan/fill (csr+rowstart+deg) + sliced G prescale
__global__ __launch_bounds__(512) void passC(const unsigned int* __restrict__ pairs,
                                             const int* __restrict__ bstart,
                                             int* __restrict__ rowstart,
                                             int* __restrict__ deg,
                                             int* __restrict__ csr,
                                             _Float16* __restrict__ G, int N) {
  __shared__ int hcnt[BSZ];
  __shared__ int lfill[BSZ];
  __shared__ int ss[512];
  __shared__ float sdinv[BSZ];
  __shared__ int lcsr[CAP];
  int b = blockIdx.x;
  int t = threadIdx.x;
  int lo = bstart[b], hi = bstart[b + 1];
  int cnt = hi - lo;
  int nbase = b << BSH;
  hcnt[t] = 0;
  __syncthreads();
  for (int k = lo + t; k < hi; k += 512)
    atomicAdd(&hcnt[(pairs[k] >> 17) & (BSZ - 1)], 1);
  __syncthreads();
  int v = hcnt[t];
  sdinv[t] = rsqrtf((float)v + 1.f);
  ss[t] = v;
  __syncthreads();
  for (int off = 1; off < 512; off <<= 1) {
    int add = (t >= off) ? ss[t - off] : 0;
    __syncthreads();
    ss[t] += add;
    __syncthreads();
  }
  int ex = ss[t] - v;
  lfill[t] = ex;
  int node = nbase + t;
  if (node < N) {
    rowstart[node] = lo + ex;
    deg[node] = v;
  }
  __syncthreads();
  bool fits = (cnt <= CAP);
  for (int k = lo + t; k < hi; k += 512) {
    unsigned int p = pairs[k];
    int pos = atomicAdd(&lfill[(p >> 17) & (BSZ - 1)], 1);
    int src = (int)(p & 0x1FFFFu);
    if (fits) lcsr[pos] = src;
    else      csr[lo + pos] = src;
  }
  __syncthreads();
  if (fits)
    for (int k = t; k < cnt; k += 512) csr[lo + k] = lcsr[k];
  // ---- in-place prescale of this bucket's sliced G rows ----
  int rows = N - nbase;
  if (rows > BSZ) rows = BSZ;
  for (int s = 0; s < 8; ++s) {
    _Float16* base = G + ((size_t)s * N + nbase) * 16;
    for (int idx = t; idx < rows * 2; idx += 512) {
      int r = idx >> 1, off = (idx & 1) * 8;
      float dv = sdinv[r];
      _Float16* p = base + (size_t)r * 16 + off;
      f16x8 vv = *(const f16x8*)p;
#pragma unroll
      for (int j = 0; j < 8; ++j) vv[j] = (_Float16)((float)vv[j] * dv);
      *(f16x8*)p = vv;
    }
  }
}

// ===== agg128r: XCD-local sliced gather, register accumulation =====
// grid = NB*8: slice = blk&7 (XCD-pinned), bucket = blk>>3.
// 16-lane group per dst node: lane-in-group lg = nb*2+half; each lane
// gathers the 16 B half-row of neighbor slot (k+nb) from the local slice,
// accumulates 8 floats in registers; shfl_xor(2/4/8) reduces over nb.
__global__ __launch_bounds__(256) void agg128r(
    const _Float16* __restrict__ Gs,           // [8][N][16] prescaled
    const int* __restrict__ csr,
    const int* __restrict__ rowstart,
    const int* __restrict__ deg,
    const float* __restrict__ bias,            // 128
    _Float16* __restrict__ x2s,                // [8][N][16] out
    int N) {
  int slice = blockIdx.x & 7;
  int b = blockIdx.x >> 3;
  int t = threadIdx.x;
  int gid = t >> 4;        // node-group 0..15 (4 per wave)
  int lg = t & 15;
  int nb = lg >> 1;        // neighbor slot 0..7
  int h8 = (lg & 1) * 8;   // channel half
  const _Float16* Gsl = Gs + (size_t)slice * (size_t)N * 16;
  int nbase = b << BSH;
  const float* bp = bias + slice * 16 + h8;
  float b4[8];
#pragma unroll
  for (int j = 0; j < 8; ++j) b4[j] = bp[j];
  for (int step = 0; step < BSZ / 16; ++step) {
    int node = nbase + step * 16 + gid;
    if (node < N) {
      int dg = deg[node];
      int s = rowstart[node];
      float a[8];
#pragma unroll
      for (int j = 0; j < 8; ++j) a[j] = 0.f;
      for (int k = 0; k < dg; k += 8) {
        int slot = k + nb;
        float w0 = (slot < dg) ? 1.f : 0.f;
        int idx = (slot < dg) ? csr[s + slot] : node;
        f16x8 v = *(const f16x8*)(Gsl + (size_t)idx * 16 + h8);
#pragma unroll
        for (int j = 0; j < 8; ++j) a[j] = fmaf(w0, (float)v[j], a[j]);
      }
#pragma unroll
      for (int j = 0; j < 8; ++j) {
        a[j] += __shfl_xor(a[j], 2);
        a[j] += __shfl_xor(a[j], 4);
        a[j] += __shfl_xor(a[j], 8);
      }
      if (nb == 0) {
        float di = rsqrtf((float)dg + 1.f);
        f16x8 sv = *(const f16x8*)(Gsl + (size_t)node * 16 + h8);
        f16x8 r;
#pragma unroll
        for (int j = 0; j < 8; ++j) {
          float val = fmaf(di, (float)sv[j] + a[j], b4[j]);
          r[j] = (_Float16)fmaxf(val, 0.f);
        }
        *(f16x8*)(x2s + ((size_t)slice * N + node) * 16 + h8) = r;
      }
    }
  }
}

// ===== agg64r: same scheme, 4 slices, row-major f32 out =====
__global__ __launch_bounds__(256) void agg64r(
    const _Float16* __restrict__ Gs,           // [4][N][16] prescaled
    const int* __restrict__ csr,
    const int* __restrict__ rowstart,
    const int* __restrict__ deg,
    const float* __restrict__ bias,            // 64
    float* __restrict__ out,                   // [N][64]
    int N) {
  int slice = blockIdx.x & 3;
  int b = blockIdx.x >> 2;
  int t = threadIdx.x;
  int gid = t >> 4;
  int lg = t & 15;
  int nb = lg >> 1;
  int h8 = (lg & 1) * 8;
  const _Float16* Gsl = Gs + (size_t)slice * (size_t)N * 16;
  int nbase = b << BSH;
  const float* bp = bias + slice * 16 + h8;
  float b4[8];
#pragma unroll
  for (int j = 0; j < 8; ++j) b4[j] = bp[j];
  for (int step = 0; step < BSZ / 16; ++step) {
    int node = nbase + step * 16 + gid;
    if (node < N) {
      int dg = deg[node];
      int s = rowstart[node];
      float a[8];
#pragma unroll
      for (int j = 0; j < 8; ++j) a[j] = 0.f;
      for (int k = 0; k < dg; k += 8) {
        int slot = k + nb;
        float w0 = (slot < dg) ? 1.f : 0.f;
        int idx = (slot < dg) ? csr[s + slot] : node;
        f16x8 v = *(const f16x8*)(Gsl + (size_t)idx * 16 + h8);
#pragma unroll
        for (int j = 0; j < 8; ++j) a[j] = fmaf(w0, (float)v[j], a[j]);
      }
#pragma unroll
      for (int j = 0; j < 8; ++j) {
        a[j] += __shfl_xor(a[j], 2);
        a[j] += __shfl_xor(a[j], 4);
        a[j] += __shfl_xor(a[j], 8);
      }
      if (nb == 0) {
        float di = rsqrtf((float)dg + 1.f);
        f16x8 sv = *(const f16x8*)(Gsl + (size_t)node * 16 + h8);
        float4 r0, r1;
        r0.x = fmaxf(fmaf(di, (float)sv[0] + a[0], b4[0]), 0.f);
        r0.y = fmaxf(fmaf(di, (float)sv[1] + a[1], b4[1]), 0.f);
        r0.z = fmaxf(fmaf(di, (float)sv[2] + a[2], b4[2]), 0.f);
        r0.w = fmaxf(fmaf(di, (float)sv[3] + a[3], b4[3]), 0.f);
        r1.x = fmaxf(fmaf(di, (float)sv[4] + a[4], b4[4]), 0.f);
        r1.y = fmaxf(fmaf(di, (float)sv[5] + a[5], b4[5]), 0.f);
        r1.z = fmaxf(fmaf(di, (float)sv[6] + a[6], b4[6]), 0.f);
        r1.w = fmaxf(fmaf(di, (float)sv[7] + a[7], b4[7]), 0.f);
        float* op = out + (size_t)node * 64 + slice * 16 + h8;
        *(float4*)op = r0;
        *(float4*)(op + 4) = r1;
      }
    }
  }
}

// ================= launch =================
extern "C" void kernel_launch(void* const* d_in, const int* in_sizes, int n_in,
                              void* d_out, int out_size, void* d_ws, size_t ws_size,
                              hipStream_t stream) {
  const float* x  = (const float*)d_in[0];
  const int*   ei = (const int*)d_in[1];
  const float* W1 = (const float*)d_in[2];
  const float* b1 = (const float*)d_in[3];
  const float* W2 = (const float*)d_in[4];
  const float* b2 = (const float*)d_in[5];
  float* out = (float*)d_out;

  const int N = in_sizes[0] / 128;
  const int E = in_sizes[1] / 2;
  const int NB = (N + BSZ - 1) >> BSH;

  char* base = (char*)d_ws;
  size_t off = 0;
  auto alloc = [&](size_t bytes) -> void* {
    void* p = base + off;
    off += (bytes + 255) & ~(size_t)255;
    return p;
  };
  int*          bcount   = (int*)alloc(256 * 4);
  int*          bstart   = (int*)alloc(260 * 4);
  int*          bfill    = (int*)alloc(256 * 4);
  int*          deg      = (int*)alloc((size_t)N * 4);
  int*          rowstart = (int*)alloc((size_t)N * 4);
  int*          csr      = (int*)alloc((size_t)E * 4);
  unsigned int* pairs    = (unsigned int*)alloc((size_t)E * 4);
  __half*       g1       = (__half*)alloc((size_t)N * 128 * 2);  // sliced; reused for G2s
  __half*       x2       = (__half*)alloc((size_t)N * 128 * 2);  // sliced

  hipMemsetAsync(bcount, 0, 256 * 4, stream);
  passA<<<512, 256, 0, stream>>>(ei, bcount, E, NB);
  scanB<<<1, 256, 0, stream>>>(bcount, bstart, bfill, NB, E);

  int GB = (N + 127) / 128;
  int PB = (E + 2047) / 2048;
  fused_gemm_passB<<<GB + PB, 256, 0, stream>>>(x, W1, (_Float16*)g1, N, GB,
                                                ei, bfill, pairs, E, PB);
  passC<<<NB, 512, 0, stream>>>(pairs, bstart, rowstart, deg, csr,
                                (_Float16*)g1, N);

  agg128r<<<NB * 8, 256, 0, stream>>>((const _Float16*)g1, csr, rowstart, deg,
                                      b1, (_Float16*)x2, N);
  int G2B = (N + 255) / 256;
  gemm2_mfma<<<G2B, 256, 0, stream>>>((const _Float16*)x2, W2, deg,
                                      (_Float16*)g1, N);
  agg64r<<<NB * 4, 256, 0, stream>>>((const _Float16*)g1, csr, rowstart, deg,
                                     b2, out, N);
}

// Round 6
// 311.703 us; speedup vs baseline: 6.4691x; 1.3281x over previous
//
#include <hip/hip_runtime.h>
#include <hip/hip_fp16.h>
#include <math.h>

typedef _Float16 f16x8 __attribute__((ext_vector_type(8)));
typedef float f32x4 __attribute__((ext_vector_type(4)));

// ================= bucketed CSR build =================
#define BSH 9
#define BSZ 512
#define CAP 12288
#define CAP2 6144

// passA: bucket histogram only (LDS atomics)
__global__ __launch_bounds__(256) void passA(const int* __restrict__ ei,
                                             int* __restrict__ bcount, int E, int NB) {
  __shared__ int hist[256];
  int t = threadIdx.x;
  hist[t] = 0;
  __syncthreads();
  for (int e = blockIdx.x * 256 + t; e < E; e += gridDim.x * 256)
    atomicAdd(&hist[ei[E + e] >> BSH], 1);
  __syncthreads();
  if (t < NB && hist[t]) atomicAdd(&bcount[t], hist[t]);
}

__global__ __launch_bounds__(256) void scanB(const int* __restrict__ bcount,
                                             int* __restrict__ bstart,
                                             int* __restrict__ bfill, int NB, int E) {
  __shared__ int s[256];
  int t = threadIdx.x;
  int v = (t < NB) ? bcount[t] : 0;
  s[t] = v;
  __syncthreads();
  for (int off = 1; off < 256; off <<= 1) {
    int add = (t >= off) ? s[t - off] : 0;
    __syncthreads();
    s[t] += add;
    __syncthreads();
  }
  if (t < NB) {
    int ex = s[t] - v;
    bstart[t] = ex;
    bfill[t] = ex;
  }
  if (t == 0) bstart[NB] = E;
}

// ===== MFMA GEMM body =====
// G output is SLICE-MAJOR, 32-ch slices: [NC/32][nrows][32] f16.
// f16 input (IN_F16) is also slice-major [4][nrows][32].
template <int NC, int NWC, bool IN_F16, bool SCALE>
__device__ __forceinline__ void gemm_mfma_body(
    const void* __restrict__ Xv, const float* __restrict__ W,
    const int* __restrict__ deg, _Float16* __restrict__ G, int nrows, int bid,
    _Float16* Bs) {
  int t = threadIdx.x;
  {
    int n = t % NC;
    int kh = (t / NC) * (NC / 2);
    constexpr int NBLK = (NC / 2) / 8;
#pragma unroll
    for (int b = 0; b < NBLK; ++b) {
      f16x8 tmp;
#pragma unroll
      for (int j = 0; j < 8; ++j)
        tmp[j] = (_Float16)W[(size_t)(kh + b * 8 + j) * NC + n];
      *(f16x8*)(&Bs[n * 136 + kh + b * 8]) = tmp;
    }
  }
  __syncthreads();

  int w = t >> 6, lane = t & 63;
  int m = lane & 15, q = lane >> 4;
  int wr = (w / NWC) * 64, wc = (w % NWC) * 64;
  int row0 = bid * ((4 / NWC) * 64);

  f32x4 acc[4][4];
#pragma unroll
  for (int rt = 0; rt < 4; ++rt)
#pragma unroll
    for (int ct = 0; ct < 4; ++ct)
#pragma unroll
      for (int qq = 0; qq < 4; ++qq) acc[rt][ct][qq] = 0.f;

#pragma unroll
  for (int kc = 0; kc < 4; ++kc) {
    int kbase = kc * 32 + q * 8;
    f16x8 af[4];
#pragma unroll
    for (int rt = 0; rt < 4; ++rt) {
      int row = row0 + wr + rt * 16 + m;
      if constexpr (IN_F16) {
        f16x8 a = {0, 0, 0, 0, 0, 0, 0, 0};
        if (row < nrows) {
          const _Float16* Xh = (const _Float16*)Xv;
          a = *(const f16x8*)(Xh + ((size_t)(kbase >> 5) * nrows + row) * 32 +
                              (kbase & 31));
        }
        af[rt] = a;
      } else {
        float4 x0 = {0, 0, 0, 0}, x1 = {0, 0, 0, 0};
        if (row < nrows) {
          const float* Xf = (const float*)Xv;
          x0 = *(const float4*)(Xf + (size_t)row * 128 + kbase);
          x1 = *(const float4*)(Xf + (size_t)row * 128 + kbase + 4);
        }
        f16x8 a;
        a[0] = (_Float16)x0.x; a[1] = (_Float16)x0.y;
        a[2] = (_Float16)x0.z; a[3] = (_Float16)x0.w;
        a[4] = (_Float16)x1.x; a[5] = (_Float16)x1.y;
        a[6] = (_Float16)x1.z; a[7] = (_Float16)x1.w;
        af[rt] = a;
      }
    }
    f16x8 bf[4];
#pragma unroll
    for (int ct = 0; ct < 4; ++ct) {
      int n = wc + ct * 16 + m;
      bf[ct] = *(f16x8*)(&Bs[n * 136 + kbase]);
    }
#pragma unroll
    for (int rt = 0; rt < 4; ++rt)
#pragma unroll
      for (int ct = 0; ct < 4; ++ct)
        acc[rt][ct] = __builtin_amdgcn_mfma_f32_16x16x32_f16(af[rt], bf[ct],
                                                             acc[rt][ct], 0, 0, 0);
  }
#pragma unroll
  for (int rt = 0; rt < 4; ++rt) {
#pragma unroll
    for (int r = 0; r < 4; ++r) {
      int row = row0 + wr + rt * 16 + q * 4 + r;
      if (row < nrows) {
        float d = SCALE ? rsqrtf((float)deg[row] + 1.f) : 1.f;
#pragma unroll
        for (int ct = 0; ct < 4; ++ct) {
          int col = wc + ct * 16 + m;
          G[((size_t)(col >> 5) * nrows + row) * 32 + (col & 31)] =
              (_Float16)(acc[rt][ct][r] * d);
        }
      }
    }
  }
}

// ===== fused: gemm1 (MFMA, unscaled, fp32-in, sliced-out) + passB =====
__global__ __launch_bounds__(256) void fused_gemm_passB(
    const float* __restrict__ X, const float* __restrict__ W1,
    _Float16* __restrict__ G, int nrows, int GB,
    const int* __restrict__ ei, int* __restrict__ bfill,
    unsigned int* __restrict__ pairs, int E, int PB) {
  __shared__ char smem[128 * 136 * 2];
  int g = blockIdx.x;
  int M2 = 2 * (GB < PB ? GB : PB);
  bool is_gemm;
  int bid;
  if (g < M2) { is_gemm = (g & 1) == 0; bid = g >> 1; }
  else        { is_gemm = (GB > PB);    bid = g - M2 + (GB < PB ? GB : PB); }
  if (is_gemm) {
    gemm_mfma_body<128, 2, false, false>(X, W1, nullptr, G, nrows, bid,
                                         (_Float16*)smem);
  } else {
    int* hist = (int*)smem;
    int* gbase = (int*)(smem + 1024);
    int t = threadIdx.x;
    hist[t] = 0;
    __syncthreads();
    int d[8], s[8], lp[8], bb[8];
    int base = bid * 2048;
#pragma unroll
    for (int u = 0; u < 8; ++u) {
      int e = base + u * 256 + t;
      if (e < E) {
        d[u] = ei[E + e];
        s[u] = ei[e];
        bb[u] = d[u] >> BSH;
        lp[u] = atomicAdd(&hist[bb[u]], 1);
      } else {
        bb[u] = -1;
      }
    }
    __syncthreads();
    if (hist[t]) gbase[t] = atomicAdd(&bfill[t], hist[t]);
    __syncthreads();
#pragma unroll
    for (int u = 0; u < 8; ++u)
      if (bb[u] >= 0)
        pairs[gbase[bb[u]] + lp[u]] =
            ((unsigned int)(d[u] & (BSZ - 1)) << 17) | (unsigned int)s[u];
  }
}

__global__ __launch_bounds__(256) void gemm2_mfma(const _Float16* __restrict__ X,
                                                  const float* __restrict__ W,
                                                  const int* __restrict__ deg,
                                                  _Float16* __restrict__ G, int nrows) {
  __shared__ _Float16 Bs[64 * 136];
  gemm_mfma_body<64, 1, true, true>(X, W, deg, G, nrows, blockIdx.x, Bs);
}

// passC: per-bucket LDS count/scan/fill (csr+rowstart+deg) + sliced G prescale
__global__ __launch_bounds__(512) void passC(const unsigned int* __restrict__ pairs,
                                             const int* __restrict__ bstart,
                                             int* __restrict__ rowstart,
                                             int* __restrict__ deg,
                                             int* __restrict__ csr,
                                             _Float16* __restrict__ G, int N) {
  __shared__ int hcnt[BSZ];
  __shared__ int lfill[BSZ];
  __shared__ int ss[512];
  __shared__ float sdinv[BSZ];
  __shared__ int lcsr[CAP];
  int b = blockIdx.x;
  int t = threadIdx.x;
  int lo = bstart[b], hi = bstart[b + 1];
  int cnt = hi - lo;
  int nbase = b << BSH;
  hcnt[t] = 0;
  __syncthreads();
  for (int k = lo + t; k < hi; k += 512)
    atomicAdd(&hcnt[(pairs[k] >> 17) & (BSZ - 1)], 1);
  __syncthreads();
  int v = hcnt[t];
  sdinv[t] = rsqrtf((float)v + 1.f);
  ss[t] = v;
  __syncthreads();
  for (int off = 1; off < 512; off <<= 1) {
    int add = (t >= off) ? ss[t - off] : 0;
    __syncthreads();
    ss[t] += add;
    __syncthreads();
  }
  int ex = ss[t] - v;
  lfill[t] = ex;
  int node = nbase + t;
  if (node < N) {
    rowstart[node] = lo + ex;
    deg[node] = v;
  }
  __syncthreads();
  bool fits = (cnt <= CAP);
  for (int k = lo + t; k < hi; k += 512) {
    unsigned int p = pairs[k];
    int pos = atomicAdd(&lfill[(p >> 17) & (BSZ - 1)], 1);
    int src = (int)(p & 0x1FFFFu);
    if (fits) lcsr[pos] = src;
    else      csr[lo + pos] = src;
  }
  __syncthreads();
  if (fits)
    for (int k = t; k < cnt; k += 512) csr[lo + k] = lcsr[k];
  // ---- in-place prescale of this bucket's sliced G rows ([4][N][32]) ----
  int rows = N - nbase;
  if (rows > BSZ) rows = BSZ;
  for (int s4 = 0; s4 < 4; ++s4) {
    _Float16* base = G + ((size_t)s4 * N + nbase) * 32;
    for (int idx = t; idx < rows * 4; idx += 512) {
      int r = idx >> 2, off = (idx & 3) * 8;
      float dv = sdinv[r];
      _Float16* p = base + (size_t)r * 32 + off;
      f16x8 vv = *(const f16x8*)p;
#pragma unroll
      for (int j = 0; j < 8; ++j) vv[j] = (_Float16)((float)vv[j] * dv);
      *(f16x8*)p = vv;
    }
  }
}

// ===== agg128q: XCD-affine 32-ch quarter gather, LDS-staged indices =====
// grid = NB*4: quarter = blk&3 (XCD pairs {x,x+4} share quarter x&3),
// bucket = blk>>2. 512 threads: 32 node-groups of 16 lanes; lane lg:
// nb = lg>>2 (neighbor slot), c8 = (lg&3)*8 (channel quad). Each lane
// gathers 16 B (8 ch) of a 64 B row; unrolled 2 slots in flight.
__global__ __launch_bounds__(512) void agg128q(
    const _Float16* __restrict__ Gs,           // [4][N][32] prescaled
    const int* __restrict__ csr,
    const int* __restrict__ rowstart,
    const int* __restrict__ deg,
    const int* __restrict__ bstart,
    const float* __restrict__ bias,            // 128
    _Float16* __restrict__ x2s,                // [4][N][32] out
    int N) {
  __shared__ int lcsr[CAP];
  __shared__ int srs[BSZ];
  __shared__ int sdg[BSZ];
  int qr = blockIdx.x & 3;
  int b = blockIdx.x >> 2;
  int t = threadIdx.x;
  int nbase = b << BSH;
  int lo = bstart[b], hi = bstart[b + 1];
  int cnt = hi - lo;
  {
    int node = nbase + t;
    srs[t] = (node < N) ? rowstart[node] - lo : 0;
    sdg[t] = (node < N) ? deg[node] : 0;
  }
  bool fits = (cnt <= CAP);
  if (fits)
    for (int k = t; k < cnt; k += 512) lcsr[k] = csr[lo + k];
  __syncthreads();

  const _Float16* Gq = Gs + (size_t)qr * (size_t)N * 32;
  int gid = t >> 4;
  int lg = t & 15;
  int nb = lg >> 2;
  int c8 = (lg & 3) * 8;
  const float* bp = bias + qr * 32 + c8;
  float bb[8];
#pragma unroll
  for (int j = 0; j < 8; ++j) bb[j] = bp[j];

  for (int step = 0; step < BSZ / 32; ++step) {
    int nl = step * 32 + gid;
    int node = nbase + nl;
    if (node < N) {
      int dgn = sdg[nl];
      int s = srs[nl];
      float a[8];
#pragma unroll
      for (int j = 0; j < 8; ++j) a[j] = 0.f;
      if (fits) {
        for (int k = 0; k < dgn; k += 8) {
          int sl0 = k + nb, sl1 = k + 4 + nb;
          int i0 = (sl0 < dgn) ? lcsr[s + sl0] : 0;
          int i1 = (sl1 < dgn) ? lcsr[s + sl1] : 0;
          float w0 = (sl0 < dgn) ? 1.f : 0.f;
          float w1 = (sl1 < dgn) ? 1.f : 0.f;
          f16x8 v0 = *(const f16x8*)(Gq + (size_t)i0 * 32 + c8);
          f16x8 v1 = *(const f16x8*)(Gq + (size_t)i1 * 32 + c8);
#pragma unroll
          for (int j = 0; j < 8; ++j) a[j] = fmaf(w0, (float)v0[j], a[j]);
#pragma unroll
          for (int j = 0; j < 8; ++j) a[j] = fmaf(w1, (float)v1[j], a[j]);
        }
      } else {
        for (int k = 0; k < dgn; k += 8) {
          int sl0 = k + nb, sl1 = k + 4 + nb;
          int i0 = (sl0 < dgn) ? csr[lo + s + sl0] : 0;
          int i1 = (sl1 < dgn) ? csr[lo + s + sl1] : 0;
          float w0 = (sl0 < dgn) ? 1.f : 0.f;
          float w1 = (sl1 < dgn) ? 1.f : 0.f;
          f16x8 v0 = *(const f16x8*)(Gq + (size_t)i0 * 32 + c8);
          f16x8 v1 = *(const f16x8*)(Gq + (size_t)i1 * 32 + c8);
#pragma unroll
          for (int j = 0; j < 8; ++j) a[j] = fmaf(w0, (float)v0[j], a[j]);
#pragma unroll
          for (int j = 0; j < 8; ++j) a[j] = fmaf(w1, (float)v1[j], a[j]);
        }
      }
#pragma unroll
      for (int j = 0; j < 8; ++j) {
        a[j] += __shfl_xor(a[j], 4);
        a[j] += __shfl_xor(a[j], 8);
      }
      if (nb == 0) {
        float di = rsqrtf((float)dgn + 1.f);
        f16x8 sv = *(const f16x8*)(Gq + (size_t)node * 32 + c8);
        f16x8 r;
#pragma unroll
        for (int j = 0; j < 8; ++j) {
          float val = fmaf(di, (float)sv[j] + a[j], bb[j]);
          r[j] = (_Float16)fmaxf(val, 0.f);
        }
        *(f16x8*)(x2s + ((size_t)qr * N + node) * 32 + c8) = r;
      }
    }
  }
}

// ===== agg64q: 2 slices x 2 node-chunks, same gather scheme, f32 out =====
// blk: slice = blk&1, chunk = (blk>>1)&1, bucket = blk>>2. 256 nodes/block.
__global__ __launch_bounds__(512) void agg64q(
    const _Float16* __restrict__ Gs,           // [2][N][32] prescaled
    const int* __restrict__ csr,
    const int* __restrict__ rowstart,
    const int* __restrict__ deg,
    const int* __restrict__ bstart,
    const float* __restrict__ bias,            // 64
    float* __restrict__ out,                   // [N][64]
    int N) {
  __shared__ int lcsr[CAP2];
  __shared__ int srs[256];
  __shared__ int sdg[256];
  int sl = blockIdx.x & 1;
  int chunk = (blockIdx.x >> 1) & 1;
  int b = blockIdx.x >> 2;
  int t = threadIdx.x;
  int nbase = (b << BSH) + chunk * 256;
  int hi_b = bstart[b + 1];
  int n1 = nbase + 256;
  int lo = (nbase < N) ? rowstart[nbase] : hi_b;
  int hi = (n1 < N) ? rowstart[n1] : hi_b;
  int cnt = hi - lo;
  if (t < 256) {
    int node = nbase + t;
    srs[t] = (node < N) ? rowstart[node] - lo : 0;
    sdg[t] = (node < N) ? deg[node] : 0;
  }
  bool fits = (cnt <= CAP2);
  if (fits)
    for (int k = t; k < cnt; k += 512) lcsr[k] = csr[lo + k];
  __syncthreads();

  const _Float16* Gq = Gs + (size_t)sl * (size_t)N * 32;
  int gid = t >> 4;
  int lg = t & 15;
  int nb = lg >> 2;
  int c8 = (lg & 3) * 8;
  const float* bp = bias + sl * 32 + c8;
  float bb[8];
#pragma unroll
  for (int j = 0; j < 8; ++j) bb[j] = bp[j];

  for (int step = 0; step < 256 / 32; ++step) {
    int nl = step * 32 + gid;
    int node = nbase + nl;
    if (node < N) {
      int dgn = sdg[nl];
      int s = srs[nl];
      float a[8];
#pragma unroll
      for (int j = 0; j < 8; ++j) a[j] = 0.f;
      if (fits) {
        for (int k = 0; k < dgn; k += 8) {
          int sl0 = k + nb, sl1 = k + 4 + nb;
          int i0 = (sl0 < dgn) ? lcsr[s + sl0] : 0;
          int i1 = (sl1 < dgn) ? lcsr[s + sl1] : 0;
          float w0 = (sl0 < dgn) ? 1.f : 0.f;
          float w1 = (sl1 < dgn) ? 1.f : 0.f;
          f16x8 v0 = *(const f16x8*)(Gq + (size_t)i0 * 32 + c8);
          f16x8 v1 = *(const f16x8*)(Gq + (size_t)i1 * 32 + c8);
#pragma unroll
          for (int j = 0; j < 8; ++j) a[j] = fmaf(w0, (float)v0[j], a[j]);
#pragma unroll
          for (int j = 0; j < 8; ++j) a[j] = fmaf(w1, (float)v1[j], a[j]);
        }
      } else {
        for (int k = 0; k < dgn; k += 8) {
          int sl0 = k + nb, sl1 = k + 4 + nb;
          int i0 = (sl0 < dgn) ? csr[lo + s + sl0] : 0;
          int i1 = (sl1 < dgn) ? csr[lo + s + sl1] : 0;
          float w0 = (sl0 < dgn) ? 1.f : 0.f;
          float w1 = (sl1 < dgn) ? 1.f : 0.f;
          f16x8 v0 = *(const f16x8*)(Gq + (size_t)i0 * 32 + c8);
          f16x8 v1 = *(const f16x8*)(Gq + (size_t)i1 * 32 + c8);
#pragma unroll
          for (int j = 0; j < 8; ++j) a[j] = fmaf(w0, (float)v0[j], a[j]);
#pragma unroll
          for (int j = 0; j < 8; ++j) a[j] = fmaf(w1, (float)v1[j], a[j]);
        }
      }
#pragma unroll
      for (int j = 0; j < 8; ++j) {
        a[j] += __shfl_xor(a[j], 4);
        a[j] += __shfl_xor(a[j], 8);
      }
      if (nb == 0) {
        float di = rsqrtf((float)dgn + 1.f);
        f16x8 sv = *(const f16x8*)(Gq + (size_t)node * 32 + c8);
        float4 r0, r1;
        r0.x = fmaxf(fmaf(di, (float)sv[0] + a[0], bb[0]), 0.f);
        r0.y = fmaxf(fmaf(di, (float)sv[1] + a[1], bb[1]), 0.f);
        r0.z = fmaxf(fmaf(di, (float)sv[2] + a[2], bb[2]), 0.f);
        r0.w = fmaxf(fmaf(di, (float)sv[3] + a[3], bb[3]), 0.f);
        r1.x = fmaxf(fmaf(di, (float)sv[4] + a[4], bb[4]), 0.f);
        r1.y = fmaxf(fmaf(di, (float)sv[5] + a[5], bb[5]), 0.f);
        r1.z = fmaxf(fmaf(di, (float)sv[6] + a[6], bb[6]), 0.f);
        r1.w = fmaxf(fmaf(di, (float)sv[7] + a[7], bb[7]), 0.f);
        float* op = out + (size_t)node * 64 + sl * 32 + c8;
        *(float4*)op = r0;
        *(float4*)(op + 4) = r1;
      }
    }
  }
}

// ================= launch =================
extern "C" void kernel_launch(void* const* d_in, const int* in_sizes, int n_in,
                              void* d_out, int out_size, void* d_ws, size_t ws_size,
                              hipStream_t stream) {
  const float* x  = (const float*)d_in[0];
  const int*   ei = (const int*)d_in[1];
  const float* W1 = (const float*)d_in[2];
  const float* b1 = (const float*)d_in[3];
  const float* W2 = (const float*)d_in[4];
  const float* b2 = (const float*)d_in[5];
  float* out = (float*)d_out;

  const int N = in_sizes[0] / 128;
  const int E = in_sizes[1] / 2;
  const int NB = (N + BSZ - 1) >> BSH;

  char* base = (char*)d_ws;
  size_t off = 0;
  auto alloc = [&](size_t bytes) -> void* {
    void* p = base + off;
    off += (bytes + 255) & ~(size_t)255;
    return p;
  };
  int*          bcount   = (int*)alloc(256 * 4);
  int*          bstart   = (int*)alloc(260 * 4);
  int*          bfill    = (int*)alloc(256 * 4);
  int*          deg      = (int*)alloc((size_t)N * 4);
  int*          rowstart = (int*)alloc((size_t)N * 4);
  int*          csr      = (int*)alloc((size_t)E * 4);
  unsigned int* pairs    = (unsigned int*)alloc((size_t)E * 4);
  __half*       g1       = (__half*)alloc((size_t)N * 128 * 2);  // sliced; reused for G2s
  __half*       x2       = (__half*)alloc((size_t)N * 128 * 2);  // sliced

  hipMemsetAsync(bcount, 0, 256 * 4, stream);
  passA<<<512, 256, 0, stream>>>(ei, bcount, E, NB);
  scanB<<<1, 256, 0, stream>>>(bcount, bstart, bfill, NB, E);

  int GB = (N + 127) / 128;
  int PB = (E + 2047) / 2048;
  fused_gemm_passB<<<GB + PB, 256, 0, stream>>>(x, W1, (_Float16*)g1, N, GB,
                                                ei, bfill, pairs, E, PB);
  passC<<<NB, 512, 0, stream>>>(pairs, bstart, rowstart, deg, csr,
                                (_Float16*)g1, N);

  agg128q<<<NB * 4, 512, 0, stream>>>((const _Float16*)g1, csr, rowstart, deg,
                                      bstart, b1, (_Float16*)x2, N);
  int G2B = (N + 255) / 256;
  gemm2_mfma<<<G2B, 256, 0, stream>>>((const _Float16*)x2, W2, deg,
                                      (_Float16*)g1, N);
  agg64q<<<NB * 4, 512, 0, stream>>>((const _Float16*)g1, csr, rowstart, deg,
                                     bstart, b2, out, N);
}